// Round 1
// 473.795 us; speedup vs baseline: 1.0425x; 1.0425x over previous
//
#include <hip/hip_runtime.h>

#define N_LOC   500000
#define N_CAT   5000
#define N_EDGES 2000000
#define DIM     128
#define NEG_SLOPE 0.2f
#define PAD     5008
#define NB      128
#define EPB     15628   // ceil(N_EDGES/NB) rounded to multiple of 4; all chunk lens are mult of 4
#define NC1     (N_CAT + 1)

// ================= K1': fused per-chunk counting sort (hist + scan + LDS scatter)
// + coalesced chunk writeout + per-chunk offset table + fused W transpose.
// Replaces old K1..K4. No scattered global writes anywhere.
__launch_bounds__(1024)
__global__ void build_kernel(const int* __restrict__ esrc, const int* __restrict__ edst,
                             const float* __restrict__ W, float* __restrict__ WT,
                             int* __restrict__ csr2, int* __restrict__ loffg) {
    int b = blockIdx.x, t = threadIdx.x;
    if (b == NB) {  // transpose W -> WT (independent work, free rider)
        for (int i = t; i < DIM * DIM; i += 1024) {
            int j = i >> 7, k = i & 127;
            WT[k * DIM + j] = W[j * DIM + k];
        }
        return;
    }
    __shared__ int lh[N_CAT];                    // 20000 B: counts -> offsets -> cursors
    __shared__ __align__(16) int sbuf[EPB];      // 62512 B: cat-sorted src values
    __shared__ int wsum[16], woff[16];

    for (int c2 = t; c2 < N_CAT; c2 += 1024) lh[c2] = 0;
    __syncthreads();

    const int s0 = b * EPB;
    const int len = min(s0 + EPB, N_EDGES) - s0;   // always a multiple of 4
    const int* dp = edst + s0;
    const int* sp = esrc + s0;

    // ---- pass 1: LDS histogram (coalesced int4 edge reads) ----
    #pragma unroll
    for (int j = 0; j < 4; ++j) {
        int off = j * 4096 + 4 * t;
        if (off < len) {
            int4 d = *(const int4*)(dp + off);
            atomicAdd(&lh[d.x], 1); atomicAdd(&lh[d.y], 1);
            atomicAdd(&lh[d.z], 1); atomicAdd(&lh[d.w], 1);
        }
    }
    __syncthreads();

    // ---- in-block exclusive scan of lh[0..5000) (5 elems/thread, 3-level) ----
    int lane = t & 63, w = t >> 6;
    int base = t * 5;                               // 5000 = 1000 threads * 5, exact
    int v0 = 0, v1 = 0, v2 = 0, v3 = 0, v4 = 0;
    if (base < N_CAT) { v0 = lh[base]; v1 = lh[base+1]; v2 = lh[base+2]; v3 = lh[base+3]; v4 = lh[base+4]; }
    int sum = v0 + v1 + v2 + v3 + v4;
    int incl = sum;
    #pragma unroll
    for (int o = 1; o < 64; o <<= 1) { int x = __shfl_up(incl, o, 64); if (lane >= o) incl += x; }
    if (lane == 63) wsum[w] = incl;
    __syncthreads();
    if (t < 16) {
        int sv = wsum[t]; int ev = sv;
        #pragma unroll
        for (int o = 1; o < 16; o <<= 1) { int x = __shfl_up(ev, o, 64); if (t >= o) ev += x; }
        woff[t] = ev - sv;                          // exclusive wave prefix
    }
    __syncthreads();
    if (base < N_CAT) {
        int run = woff[w] + (incl - sum);           // thread's exclusive base
        lh[base]     = run; run += v0;
        lh[base + 1] = run; run += v1;
        lh[base + 2] = run; run += v2;
        lh[base + 3] = run; run += v3;
        lh[base + 4] = run;
    }
    __syncthreads();

    // ---- write per-chunk offset table (coalesced; lh still holds pristine offsets) ----
    for (int c2 = t; c2 < N_CAT; c2 += 1024) loffg[(size_t)b * NC1 + c2] = lh[c2];
    if (t == 0) loffg[(size_t)b * NC1 + N_CAT] = len;
    __syncthreads();

    // ---- pass 2: cursor scatter of src values into LDS (lh becomes cursors) ----
    #pragma unroll
    for (int j = 0; j < 4; ++j) {
        int off = j * 4096 + 4 * t;
        if (off < len) {
            int4 d = *(const int4*)(dp + off);
            int4 s = *(const int4*)(sp + off);
            int p0 = atomicAdd(&lh[d.x], 1); sbuf[p0] = s.x;
            int p1 = atomicAdd(&lh[d.y], 1); sbuf[p1] = s.y;
            int p2 = atomicAdd(&lh[d.z], 1); sbuf[p2] = s.z;
            int p3 = atomicAdd(&lh[d.w], 1); sbuf[p3] = s.w;
        }
    }
    __syncthreads();

    // ---- coalesced chunk writeout ----
    int* cout = csr2 + s0;
    for (int i = 4 * t; i < len; i += 4096)
        *(int4*)(cout + i) = *(const int4*)(sbuf + i);
}

// ================= K2': fused aggregate + linear + LeakyReLU over per-chunk segments
// one block per cat; 8 groups x 32 lanes; group g walks chunks [g*16, g*16+16).
__launch_bounds__(256)
__global__ void agg2_kernel(const float* __restrict__ loc, const int* __restrict__ csr2,
                            const int* __restrict__ loffg, const float* __restrict__ WT,
                            const float* __restrict__ bias, float* __restrict__ out) {
    __shared__ float4 sacc[256];   // reused as float sred[1024]
    __shared__ float  srow[DIM];
    int bid = blockIdx.x;
    // bijective XCD swizzle: each XCD owns a contiguous cat range (5000 = 8*625)
    int c = (bid & 7) * (N_CAT / 8) + (bid >> 3);
    int t = threadIdx.x;
    int g = t >> 5;
    int l = t & 31;

    float4 a0 = make_float4(0.f, 0.f, 0.f, 0.f);
    float4 a1 = a0, a2 = a0, a3 = a0;

    int bb = g * (NB / 8);
    int s = loffg[(size_t)bb * NC1 + c];
    int e = loffg[(size_t)bb * NC1 + c + 1];
    for (int ib = 0; ib < NB / 8; ++ib) {
        int ns = 0, ne = 0;
        if (ib + 1 < NB / 8) {   // prefetch next chunk's bounds (adjacent ints, 1 line)
            ns = loffg[(size_t)(bb + 1) * NC1 + c];
            ne = loffg[(size_t)(bb + 1) * NC1 + c + 1];
        }
        const int* cp = csr2 + (size_t)bb * EPB;
        int p = s;
        for (; p + 4 <= e; p += 4) {
            int s0 = cp[p], s1 = cp[p + 1], s2 = cp[p + 2], s3 = cp[p + 3];
            float4 v0 = ((const float4*)(loc + (size_t)s0 * DIM))[l];
            float4 v1 = ((const float4*)(loc + (size_t)s1 * DIM))[l];
            float4 v2 = ((const float4*)(loc + (size_t)s2 * DIM))[l];
            float4 v3 = ((const float4*)(loc + (size_t)s3 * DIM))[l];
            a0.x += v0.x; a0.y += v0.y; a0.z += v0.z; a0.w += v0.w;
            a1.x += v1.x; a1.y += v1.y; a1.z += v1.z; a1.w += v1.w;
            a2.x += v2.x; a2.y += v2.y; a2.z += v2.z; a2.w += v2.w;
            a3.x += v3.x; a3.y += v3.y; a3.z += v3.z; a3.w += v3.w;
        }
        for (; p < e; ++p) {
            int sx = cp[p];
            float4 v = ((const float4*)(loc + (size_t)sx * DIM))[l];
            a0.x += v.x; a0.y += v.y; a0.z += v.z; a0.w += v.w;
        }
        s = ns; e = ne; ++bb;
    }

    float4 acc = make_float4((a0.x + a1.x) + (a2.x + a3.x),
                             (a0.y + a1.y) + (a2.y + a3.y),
                             (a0.z + a1.z) + (a2.z + a3.z),
                             (a0.w + a1.w) + (a2.w + a3.w));
    sacc[t] = acc;
    __syncthreads();
    if (t < 128) {
        float4 a = sacc[t], b = sacc[t + 128];
        sacc[t] = make_float4(a.x + b.x, a.y + b.y, a.z + b.z, a.w + b.w);
    }
    __syncthreads();
    if (t < 64) {
        float4 a = sacc[t], b = sacc[t + 64];
        sacc[t] = make_float4(a.x + b.x, a.y + b.y, a.z + b.z, a.w + b.w);
    }
    __syncthreads();
    if (t < 32) {
        float4 a = sacc[t], b = sacc[t + 32];
        srow[4 * t + 0] = a.x + b.x;
        srow[4 * t + 1] = a.y + b.y;
        srow[4 * t + 2] = a.z + b.z;
        srow[4 * t + 3] = a.w + b.w;
    }
    __syncthreads();
    int j = t & 127;
    int h = t >> 7;
    float m0 = 0.f, m1 = 0.f, m2 = 0.f, m3 = 0.f;
    int k0 = h * 64;
    #pragma unroll 4
    for (int k = 0; k < 64; k += 4) {
        m0 += WT[(k0 + k + 0) * DIM + j] * srow[k0 + k + 0];
        m1 += WT[(k0 + k + 1) * DIM + j] * srow[k0 + k + 1];
        m2 += WT[(k0 + k + 2) * DIM + j] * srow[k0 + k + 2];
        m3 += WT[(k0 + k + 3) * DIM + j] * srow[k0 + k + 3];
    }
    float* sred = (float*)sacc;
    sred[t] = (m0 + m1) + (m2 + m3);
    __syncthreads();
    if (t < 128) {
        float v = sred[t] + sred[t + 128] + bias[t];
        v = v > 0.f ? v : NEG_SLOPE * v;
        out[(size_t)c * DIM + t] = v;
    }
}

// ================= fallback paths (unchanged) =================

__global__ void hist_rank_kernel(const int* __restrict__ dst, int* __restrict__ cnt,
                                 int* __restrict__ rank, int n) {
    int i = blockIdx.x * blockDim.x + threadIdx.x;
    if (i < n) rank[i] = atomicAdd(&cnt[dst[i]], 1);
}

__global__ void fill_rank_kernel(const int* __restrict__ src, const int* __restrict__ dst,
                                 const int* __restrict__ rank, const int* __restrict__ offsets,
                                 int* __restrict__ csr_src, int n) {
    int i = blockIdx.x * blockDim.x + threadIdx.x;
    if (i < n) csr_src[offsets[dst[i]] + rank[i]] = src[i];
}

__global__ void transpose_kernel(const float* __restrict__ W, float* __restrict__ WT) {
    int j = blockIdx.x;
    int k = threadIdx.x;
    WT[k * DIM + j] = W[j * DIM + k];
}

__global__ void zero_kernel(float* p, int n) {
    int i = blockIdx.x * blockDim.x + threadIdx.x;
    if (i < n) p[i] = 0.f;
}

__launch_bounds__(1024)
__global__ void scan_kernel(const int* __restrict__ cnt, int* __restrict__ offsets) {
    __shared__ int wsum[16];
    __shared__ int woff[16];
    __shared__ int total_s, running_s;
    int t = threadIdx.x;
    int lane = t & 63, w = t >> 6;
    if (t == 0) { running_s = 0; offsets[0] = 0; }
    __syncthreads();
    for (int base = 0; base < N_CAT; base += 1024) {
        int i = base + t;
        int v = (i < N_CAT) ? cnt[i] : 0;
        int incl = v;
        #pragma unroll
        for (int off = 1; off < 64; off <<= 1) {
            int x = __shfl_up(incl, off, 64);
            if (lane >= off) incl += x;
        }
        if (lane == 63) wsum[w] = incl;
        __syncthreads();
        if (w == 0 && lane < 16) {
            int s = wsum[lane];
            int e = s;
            #pragma unroll
            for (int off = 1; off < 16; off <<= 1) {
                int x = __shfl_up(e, off, 64);
                if (lane >= off) e += x;
            }
            woff[lane] = e - s;
            if (lane == 15) total_s = e;
        }
        __syncthreads();
        int run = running_s;
        if (i < N_CAT) offsets[i + 1] = run + woff[w] + incl;
        __syncthreads();
        if (t == 0) running_s = run + total_s;
        __syncthreads();
    }
}

__launch_bounds__(256)
__global__ void agg_fused_kernel(const float* __restrict__ loc, const int* __restrict__ csr_src,
                                 const int* __restrict__ offsets, const float* __restrict__ WT,
                                 const float* __restrict__ bias, float* __restrict__ out) {
    __shared__ float4 sacc[256];
    __shared__ float  srow[DIM];
    int c = blockIdx.x;
    int t = threadIdx.x;
    int g = t >> 5;
    int l = t & 31;
    int beg = offsets[c];
    int end = offsets[c + 1];
    int cnt = end - beg;
    int per = (cnt + 7) >> 3;
    int gbeg = beg + g * per;
    int gend = min(gbeg + per, end);

    float4 a0 = make_float4(0.f, 0.f, 0.f, 0.f);
    float4 a1 = a0, a2 = a0, a3 = a0;
    int e = gbeg;
    for (; e + 4 <= gend; e += 4) {
        int s0 = csr_src[e + 0], s1 = csr_src[e + 1], s2 = csr_src[e + 2], s3 = csr_src[e + 3];
        float4 v0 = ((const float4*)(loc + (size_t)s0 * DIM))[l];
        float4 v1 = ((const float4*)(loc + (size_t)s1 * DIM))[l];
        float4 v2 = ((const float4*)(loc + (size_t)s2 * DIM))[l];
        float4 v3 = ((const float4*)(loc + (size_t)s3 * DIM))[l];
        a0.x += v0.x; a0.y += v0.y; a0.z += v0.z; a0.w += v0.w;
        a1.x += v1.x; a1.y += v1.y; a1.z += v1.z; a1.w += v1.w;
        a2.x += v2.x; a2.y += v2.y; a2.z += v2.z; a2.w += v2.w;
        a3.x += v3.x; a3.y += v3.y; a3.z += v3.z; a3.w += v3.w;
    }
    for (; e < gend; ++e) {
        int s = csr_src[e];
        float4 v = ((const float4*)(loc + (size_t)s * DIM))[l];
        a0.x += v.x; a0.y += v.y; a0.z += v.z; a0.w += v.w;
    }
    float4 acc = make_float4((a0.x + a1.x) + (a2.x + a3.x),
                             (a0.y + a1.y) + (a2.y + a3.y),
                             (a0.z + a1.z) + (a2.z + a3.z),
                             (a0.w + a1.w) + (a2.w + a3.w));
    sacc[t] = acc;
    __syncthreads();
    if (t < 128) {
        float4 a = sacc[t], b = sacc[t + 128];
        sacc[t] = make_float4(a.x + b.x, a.y + b.y, a.z + b.z, a.w + b.w);
    }
    __syncthreads();
    if (t < 64) {
        float4 a = sacc[t], b = sacc[t + 64];
        sacc[t] = make_float4(a.x + b.x, a.y + b.y, a.z + b.z, a.w + b.w);
    }
    __syncthreads();
    if (t < 32) {
        float4 a = sacc[t], b = sacc[t + 32];
        srow[4 * t + 0] = a.x + b.x;
        srow[4 * t + 1] = a.y + b.y;
        srow[4 * t + 2] = a.z + b.z;
        srow[4 * t + 3] = a.w + b.w;
    }
    __syncthreads();
    int j = t & 127;
    int h = t >> 7;
    float m0 = 0.f, m1 = 0.f, m2 = 0.f, m3 = 0.f;
    int k0 = h * 64;
    #pragma unroll 4
    for (int k = 0; k < 64; k += 4) {
        m0 += WT[(k0 + k + 0) * DIM + j] * srow[k0 + k + 0];
        m1 += WT[(k0 + k + 1) * DIM + j] * srow[k0 + k + 1];
        m2 += WT[(k0 + k + 2) * DIM + j] * srow[k0 + k + 2];
        m3 += WT[(k0 + k + 3) * DIM + j] * srow[k0 + k + 3];
    }
    float* sred = (float*)sacc;
    sred[t] = (m0 + m1) + (m2 + m3);
    __syncthreads();
    if (t < 128) {
        float v = sred[t] + sred[t + 128] + bias[t];
        v = v > 0.f ? v : NEG_SLOPE * v;
        out[(size_t)c * DIM + t] = v;
    }
}

__launch_bounds__(128)
__global__ void scatter_atomic_kernel(const float* __restrict__ loc, const int* __restrict__ src,
                                      const int* __restrict__ dst, float* __restrict__ agg) {
    int e = blockIdx.x;
    int d = threadIdx.x;
    atomicAdd(&agg[(size_t)dst[e] * DIM + d], loc[(size_t)src[e] * DIM + d]);
}

#define CATS_PER_BLOCK 8
__launch_bounds__(256)
__global__ void gemm_lrelu_kernel(const float* __restrict__ agg, const float* __restrict__ W,
                                  const float* __restrict__ b, float* __restrict__ out) {
    __shared__ float sW[DIM * 129];
    __shared__ float sA[CATS_PER_BLOCK * DIM];
    int t = threadIdx.x;
    int cbase = blockIdx.x * CATS_PER_BLOCK;
    for (int i = t; i < DIM * DIM; i += 256) {
        int j = i >> 7, k = i & 127;
        sW[j * 129 + k] = W[i];
    }
    for (int i = t; i < CATS_PER_BLOCK * DIM; i += 256)
        sA[i] = agg[(size_t)cbase * DIM + i];
    __syncthreads();
    int j = t & 127;
    int cc = t >> 7;
    float acc0 = 0.f, acc1 = 0.f, acc2 = 0.f, acc3 = 0.f;
    for (int k = 0; k < DIM; ++k) {
        float w = sW[j * 129 + k];
        acc0 += w * sA[(cc + 0) * DIM + k];
        acc1 += w * sA[(cc + 2) * DIM + k];
        acc2 += w * sA[(cc + 4) * DIM + k];
        acc3 += w * sA[(cc + 6) * DIM + k];
    }
    float bj = b[j];
    float r0 = acc0 + bj, r1 = acc1 + bj, r2 = acc2 + bj, r3 = acc3 + bj;
    r0 = r0 > 0.f ? r0 : NEG_SLOPE * r0;
    r1 = r1 > 0.f ? r1 : NEG_SLOPE * r1;
    r2 = r2 > 0.f ? r2 : NEG_SLOPE * r2;
    r3 = r3 > 0.f ? r3 : NEG_SLOPE * r3;
    out[(size_t)(cbase + cc + 0) * DIM + j] = r0;
    out[(size_t)(cbase + cc + 2) * DIM + j] = r1;
    out[(size_t)(cbase + cc + 4) * DIM + j] = r2;
    out[(size_t)(cbase + cc + 6) * DIM + j] = r3;
}

extern "C" void kernel_launch(void* const* d_in, const int* in_sizes, int n_in,
                              void* d_out, int out_size, void* d_ws, size_t ws_size,
                              hipStream_t stream) {
    const float* loc  = (const float*)d_in[0];
    const float* W    = (const float*)d_in[1];
    const float* bias = (const float*)d_in[2];
    const int*   esrc = (const int*)d_in[3];
    const int*   edst = (const int*)d_in[4];
    float* out = (float*)d_out;

    size_t need_new  = ((size_t)N_EDGES + (size_t)NB * NC1 + DIM * DIM) * sizeof(int);
    size_t need_rank = ((size_t)2 * N_EDGES + 2 * PAD + DIM * DIM) * sizeof(int);

    if (ws_size >= need_new) {
        int*   csr2  = (int*)d_ws;                         // [N_EDGES] chunk-major, cat-sorted within chunk
        int*   loffg = csr2 + N_EDGES;                     // [NB * (N_CAT+1)] per-chunk offsets
        float* WT    = (float*)(loffg + (size_t)NB * NC1); // [DIM*DIM]

        build_kernel<<<NB + 1, 1024, 0, stream>>>(esrc, edst, W, WT, csr2, loffg);
        agg2_kernel<<<N_CAT, 256, 0, stream>>>(loc, csr2, loffg, WT, bias, out);
    } else if (ws_size >= need_rank) {
        int* counts  = (int*)d_ws;
        int* offsets = counts + PAD;
        float* WT    = (float*)(offsets + PAD);
        int* rank    = (int*)(WT + DIM * DIM);
        int* csr_src = rank + N_EDGES;

        hipMemsetAsync(counts, 0, (size_t)PAD * sizeof(int), stream);
        transpose_kernel<<<DIM, DIM, 0, stream>>>(W, WT);
        const int eblocks = (N_EDGES + 255) / 256;
        hist_rank_kernel<<<eblocks, 256, 0, stream>>>(edst, counts, rank, N_EDGES);
        scan_kernel<<<1, 1024, 0, stream>>>(counts, offsets);
        fill_rank_kernel<<<eblocks, 256, 0, stream>>>(esrc, edst, rank, offsets, csr_src, N_EDGES);
        agg_fused_kernel<<<N_CAT, 256, 0, stream>>>(loc, csr_src, offsets, WT, bias, out);
    } else {
        int n = N_CAT * DIM;
        zero_kernel<<<(n + 255) / 256, 256, 0, stream>>>(out, n);
        scatter_atomic_kernel<<<N_EDGES, DIM, 0, stream>>>(loc, esrc, edst, out);
        gemm_lrelu_kernel<<<N_CAT / CATS_PER_BLOCK, 256, 0, stream>>>(out, W, bias, out);
    }
}

// Round 2
// 456.975 us; speedup vs baseline: 1.0808x; 1.0368x over previous
//
#include <hip/hip_runtime.h>

#define N_LOC   500000
#define N_CAT   5000
#define N_EDGES 2000000
#define DIM     128
#define NEG_SLOPE 0.2f
#define PAD     5008
#define NB      256
#define EPB     7816    // ceil(N_EDGES/NB) rounded to mult of 4; last chunk = 6920 (mult of 4)
#define NC1     (N_CAT + 1)
#define SLIST   2048    // per-cat LDS edge list capacity (mean 400, stat-max ~490)

// ================= K1: fused per-chunk counting sort (hist + scan + LDS scatter)
// 256 chunks (1 per CU), 51.4 KB LDS. No scattered global writes anywhere.
__launch_bounds__(1024)
__global__ void build_kernel(const int* __restrict__ esrc, const int* __restrict__ edst,
                             const float* __restrict__ W, float* __restrict__ WT,
                             int* __restrict__ csr2, int* __restrict__ loffg) {
    int b = blockIdx.x, t = threadIdx.x;
    if (b == NB) {  // transpose W -> WT (independent work, free rider)
        for (int i = t; i < DIM * DIM; i += 1024) {
            int j = i >> 7, k = i & 127;
            WT[k * DIM + j] = W[j * DIM + k];
        }
        return;
    }
    __shared__ int lh[N_CAT];                    // 20000 B: counts -> offsets -> cursors
    __shared__ __align__(16) int sbuf[EPB];      // 31264 B: cat-sorted src values
    __shared__ int wsum[16], woff[16];

    for (int c2 = t; c2 < N_CAT; c2 += 1024) lh[c2] = 0;
    __syncthreads();

    const int s0 = b * EPB;
    const int len = min(s0 + EPB, N_EDGES) - s0;   // always a multiple of 4
    const int* dp = edst + s0;
    const int* sp = esrc + s0;

    // ---- pass 1: LDS histogram (coalesced int4 edge reads) ----
    #pragma unroll
    for (int j = 0; j < 2; ++j) {
        int off = j * 4096 + 4 * t;
        if (off < len) {
            int4 d = *(const int4*)(dp + off);
            atomicAdd(&lh[d.x], 1); atomicAdd(&lh[d.y], 1);
            atomicAdd(&lh[d.z], 1); atomicAdd(&lh[d.w], 1);
        }
    }
    __syncthreads();

    // ---- in-block exclusive scan of lh[0..5000) (5 elems/thread, 3-level) ----
    int lane = t & 63, w = t >> 6;
    int base = t * 5;                               // 5000 = 1000 threads * 5, exact
    int v0 = 0, v1 = 0, v2 = 0, v3 = 0, v4 = 0;
    if (base < N_CAT) { v0 = lh[base]; v1 = lh[base+1]; v2 = lh[base+2]; v3 = lh[base+3]; v4 = lh[base+4]; }
    int sum = v0 + v1 + v2 + v3 + v4;
    int incl = sum;
    #pragma unroll
    for (int o = 1; o < 64; o <<= 1) { int x = __shfl_up(incl, o, 64); if (lane >= o) incl += x; }
    if (lane == 63) wsum[w] = incl;
    __syncthreads();
    if (t < 16) {
        int sv = wsum[t]; int ev = sv;
        #pragma unroll
        for (int o = 1; o < 16; o <<= 1) { int x = __shfl_up(ev, o, 64); if (t >= o) ev += x; }
        woff[t] = ev - sv;                          // exclusive wave prefix
    }
    __syncthreads();
    if (base < N_CAT) {
        int run = woff[w] + (incl - sum);           // thread's exclusive base
        lh[base]     = run; run += v0;
        lh[base + 1] = run; run += v1;
        lh[base + 2] = run; run += v2;
        lh[base + 3] = run; run += v3;
        lh[base + 4] = run;
    }
    __syncthreads();

    // ---- write per-chunk offset table (coalesced; lh still holds pristine offsets) ----
    for (int c2 = t; c2 < N_CAT; c2 += 1024) loffg[(size_t)b * NC1 + c2] = lh[c2];
    if (t == 0) loffg[(size_t)b * NC1 + N_CAT] = len;
    __syncthreads();

    // ---- pass 2: cursor scatter of src values into LDS (lh becomes cursors) ----
    #pragma unroll
    for (int j = 0; j < 2; ++j) {
        int off = j * 4096 + 4 * t;
        if (off < len) {
            int4 d = *(const int4*)(dp + off);
            int4 s = *(const int4*)(sp + off);
            int p0 = atomicAdd(&lh[d.x], 1); sbuf[p0] = s.x;
            int p1 = atomicAdd(&lh[d.y], 1); sbuf[p1] = s.y;
            int p2 = atomicAdd(&lh[d.z], 1); sbuf[p2] = s.z;
            int p3 = atomicAdd(&lh[d.w], 1); sbuf[p3] = s.w;
        }
    }
    __syncthreads();

    // ---- coalesced chunk writeout ----
    int* cout = csr2 + s0;
    for (int i = 4 * t; i < len; i += 4096)
        *(int4*)(cout + i) = *(const int4*)(sbuf + i);
}

// ================= K2: LDS-staged aggregate + linear + LeakyReLU
// one block per cat. Stage: thread t copies chunk t's segment into slist (block scan
// for placement). Gather: 8 groups x 32 lanes over the contiguous LDS list, 8-way unroll.
__launch_bounds__(256)
__global__ void agg3_kernel(const float* __restrict__ loc, const int* __restrict__ csr2,
                            const int* __restrict__ loffg, const float* __restrict__ WT,
                            const float* __restrict__ bias, float* __restrict__ out) {
    __shared__ float4 sacc[256];   // reused as float sred[1024]
    __shared__ float  srow[DIM];
    __shared__ int    slist[SLIST];
    __shared__ int    wsum4[4], woff4[4], tot_s;
    int bid = blockIdx.x;
    // bijective XCD swizzle: each XCD owns a contiguous cat range (5000 = 8*625)
    int c = (bid & 7) * (N_CAT / 8) + (bid >> 3);
    int t = threadIdx.x;
    int lane = t & 63, w = t >> 6;

    // ---- stage: gather chunk t's segment bounds, block-scan, copy into slist ----
    int sOff = loffg[(size_t)t * NC1 + c];
    int cnt  = loffg[(size_t)t * NC1 + c + 1] - sOff;
    int incl = cnt;
    #pragma unroll
    for (int o = 1; o < 64; o <<= 1) { int x = __shfl_up(incl, o, 64); if (lane >= o) incl += x; }
    if (lane == 63) wsum4[w] = incl;
    __syncthreads();
    if (t == 0) {
        int r = 0;
        #pragma unroll
        for (int i = 0; i < 4; ++i) { woff4[i] = r; r += wsum4[i]; }
        tot_s = r;
    }
    __syncthreads();
    int sbase = woff4[w] + (incl - cnt);
    const int* seg = csr2 + (size_t)t * EPB + sOff;
    int lim = min(cnt, max(0, SLIST - sbase));   // safety clamp (never hit statistically)
    for (int k = 0; k < lim; ++k) slist[sbase + k] = seg[k];
    __syncthreads();
    int total = min(tot_s, SLIST);

    // ---- gather: 8 groups x 32 lanes, contiguous runs, 8 row-loads in flight ----
    int g = t >> 5;
    int l = t & 31;
    int per  = (total + 7) >> 3;
    int gbeg = g * per;
    int gend = min(gbeg + per, total);

    float4 a0 = make_float4(0.f, 0.f, 0.f, 0.f);
    float4 a1 = a0, a2 = a0, a3 = a0;
    int e = gbeg;
    for (; e + 8 <= gend; e += 8) {
        int s0 = slist[e + 0], s1 = slist[e + 1], s2 = slist[e + 2], s3 = slist[e + 3];
        int s4 = slist[e + 4], s5 = slist[e + 5], s6 = slist[e + 6], s7 = slist[e + 7];
        float4 v0 = ((const float4*)(loc + (size_t)s0 * DIM))[l];
        float4 v1 = ((const float4*)(loc + (size_t)s1 * DIM))[l];
        float4 v2 = ((const float4*)(loc + (size_t)s2 * DIM))[l];
        float4 v3 = ((const float4*)(loc + (size_t)s3 * DIM))[l];
        float4 v4 = ((const float4*)(loc + (size_t)s4 * DIM))[l];
        float4 v5 = ((const float4*)(loc + (size_t)s5 * DIM))[l];
        float4 v6 = ((const float4*)(loc + (size_t)s6 * DIM))[l];
        float4 v7 = ((const float4*)(loc + (size_t)s7 * DIM))[l];
        a0.x += v0.x; a0.y += v0.y; a0.z += v0.z; a0.w += v0.w;
        a1.x += v1.x; a1.y += v1.y; a1.z += v1.z; a1.w += v1.w;
        a2.x += v2.x; a2.y += v2.y; a2.z += v2.z; a2.w += v2.w;
        a3.x += v3.x; a3.y += v3.y; a3.z += v3.z; a3.w += v3.w;
        a0.x += v4.x; a0.y += v4.y; a0.z += v4.z; a0.w += v4.w;
        a1.x += v5.x; a1.y += v5.y; a1.z += v5.z; a1.w += v5.w;
        a2.x += v6.x; a2.y += v6.y; a2.z += v6.z; a2.w += v6.w;
        a3.x += v7.x; a3.y += v7.y; a3.z += v7.z; a3.w += v7.w;
    }
    for (; e + 4 <= gend; e += 4) {
        int s0 = slist[e + 0], s1 = slist[e + 1], s2 = slist[e + 2], s3 = slist[e + 3];
        float4 v0 = ((const float4*)(loc + (size_t)s0 * DIM))[l];
        float4 v1 = ((const float4*)(loc + (size_t)s1 * DIM))[l];
        float4 v2 = ((const float4*)(loc + (size_t)s2 * DIM))[l];
        float4 v3 = ((const float4*)(loc + (size_t)s3 * DIM))[l];
        a0.x += v0.x; a0.y += v0.y; a0.z += v0.z; a0.w += v0.w;
        a1.x += v1.x; a1.y += v1.y; a1.z += v1.z; a1.w += v1.w;
        a2.x += v2.x; a2.y += v2.y; a2.z += v2.z; a2.w += v2.w;
        a3.x += v3.x; a3.y += v3.y; a3.z += v3.z; a3.w += v3.w;
    }
    for (; e < gend; ++e) {
        int s = slist[e];
        float4 v = ((const float4*)(loc + (size_t)s * DIM))[l];
        a0.x += v.x; a0.y += v.y; a0.z += v.z; a0.w += v.w;
    }

    float4 acc = make_float4((a0.x + a1.x) + (a2.x + a3.x),
                             (a0.y + a1.y) + (a2.y + a3.y),
                             (a0.z + a1.z) + (a2.z + a3.z),
                             (a0.w + a1.w) + (a2.w + a3.w));
    sacc[t] = acc;
    __syncthreads();
    if (t < 128) {
        float4 a = sacc[t], b = sacc[t + 128];
        sacc[t] = make_float4(a.x + b.x, a.y + b.y, a.z + b.z, a.w + b.w);
    }
    __syncthreads();
    if (t < 64) {
        float4 a = sacc[t], b = sacc[t + 64];
        sacc[t] = make_float4(a.x + b.x, a.y + b.y, a.z + b.z, a.w + b.w);
    }
    __syncthreads();
    if (t < 32) {
        float4 a = sacc[t], b = sacc[t + 32];
        srow[4 * t + 0] = a.x + b.x;
        srow[4 * t + 1] = a.y + b.y;
        srow[4 * t + 2] = a.z + b.z;
        srow[4 * t + 3] = a.w + b.w;
    }
    __syncthreads();
    int j = t & 127;
    int h = t >> 7;
    float m0 = 0.f, m1 = 0.f, m2 = 0.f, m3 = 0.f;
    int k0 = h * 64;
    #pragma unroll 4
    for (int k = 0; k < 64; k += 4) {
        m0 += WT[(k0 + k + 0) * DIM + j] * srow[k0 + k + 0];
        m1 += WT[(k0 + k + 1) * DIM + j] * srow[k0 + k + 1];
        m2 += WT[(k0 + k + 2) * DIM + j] * srow[k0 + k + 2];
        m3 += WT[(k0 + k + 3) * DIM + j] * srow[k0 + k + 3];
    }
    float* sred = (float*)sacc;
    sred[t] = (m0 + m1) + (m2 + m3);
    __syncthreads();
    if (t < 128) {
        float v = sred[t] + sred[t + 128] + bias[t];
        v = v > 0.f ? v : NEG_SLOPE * v;
        out[(size_t)c * DIM + t] = v;
    }
}

// ================= fallback paths (unchanged) =================

__global__ void hist_rank_kernel(const int* __restrict__ dst, int* __restrict__ cnt,
                                 int* __restrict__ rank, int n) {
    int i = blockIdx.x * blockDim.x + threadIdx.x;
    if (i < n) rank[i] = atomicAdd(&cnt[dst[i]], 1);
}

__global__ void fill_rank_kernel(const int* __restrict__ src, const int* __restrict__ dst,
                                 const int* __restrict__ rank, const int* __restrict__ offsets,
                                 int* __restrict__ csr_src, int n) {
    int i = blockIdx.x * blockDim.x + threadIdx.x;
    if (i < n) csr_src[offsets[dst[i]] + rank[i]] = src[i];
}

__global__ void transpose_kernel(const float* __restrict__ W, float* __restrict__ WT) {
    int j = blockIdx.x;
    int k = threadIdx.x;
    WT[k * DIM + j] = W[j * DIM + k];
}

__global__ void zero_kernel(float* p, int n) {
    int i = blockIdx.x * blockDim.x + threadIdx.x;
    if (i < n) p[i] = 0.f;
}

__launch_bounds__(1024)
__global__ void scan_kernel(const int* __restrict__ cnt, int* __restrict__ offsets) {
    __shared__ int wsum[16];
    __shared__ int woff[16];
    __shared__ int total_s, running_s;
    int t = threadIdx.x;
    int lane = t & 63, w = t >> 6;
    if (t == 0) { running_s = 0; offsets[0] = 0; }
    __syncthreads();
    for (int base = 0; base < N_CAT; base += 1024) {
        int i = base + t;
        int v = (i < N_CAT) ? cnt[i] : 0;
        int incl = v;
        #pragma unroll
        for (int off = 1; off < 64; off <<= 1) {
            int x = __shfl_up(incl, off, 64);
            if (lane >= off) incl += x;
        }
        if (lane == 63) wsum[w] = incl;
        __syncthreads();
        if (w == 0 && lane < 16) {
            int s = wsum[lane];
            int e = s;
            #pragma unroll
            for (int off = 1; off < 16; off <<= 1) {
                int x = __shfl_up(e, off, 64);
                if (lane >= off) e += x;
            }
            woff[lane] = e - s;
            if (lane == 15) total_s = e;
        }
        __syncthreads();
        int run = running_s;
        if (i < N_CAT) offsets[i + 1] = run + woff[w] + incl;
        __syncthreads();
        if (t == 0) running_s = run + total_s;
        __syncthreads();
    }
}

__launch_bounds__(256)
__global__ void agg_fused_kernel(const float* __restrict__ loc, const int* __restrict__ csr_src,
                                 const int* __restrict__ offsets, const float* __restrict__ WT,
                                 const float* __restrict__ bias, float* __restrict__ out) {
    __shared__ float4 sacc[256];
    __shared__ float  srow[DIM];
    int c = blockIdx.x;
    int t = threadIdx.x;
    int g = t >> 5;
    int l = t & 31;
    int beg = offsets[c];
    int end = offsets[c + 1];
    int cnt = end - beg;
    int per = (cnt + 7) >> 3;
    int gbeg = beg + g * per;
    int gend = min(gbeg + per, end);

    float4 a0 = make_float4(0.f, 0.f, 0.f, 0.f);
    float4 a1 = a0, a2 = a0, a3 = a0;
    int e = gbeg;
    for (; e + 4 <= gend; e += 4) {
        int s0 = csr_src[e + 0], s1 = csr_src[e + 1], s2 = csr_src[e + 2], s3 = csr_src[e + 3];
        float4 v0 = ((const float4*)(loc + (size_t)s0 * DIM))[l];
        float4 v1 = ((const float4*)(loc + (size_t)s1 * DIM))[l];
        float4 v2 = ((const float4*)(loc + (size_t)s2 * DIM))[l];
        float4 v3 = ((const float4*)(loc + (size_t)s3 * DIM))[l];
        a0.x += v0.x; a0.y += v0.y; a0.z += v0.z; a0.w += v0.w;
        a1.x += v1.x; a1.y += v1.y; a1.z += v1.z; a1.w += v1.w;
        a2.x += v2.x; a2.y += v2.y; a2.z += v2.z; a2.w += v2.w;
        a3.x += v3.x; a3.y += v3.y; a3.z += v3.z; a3.w += v3.w;
    }
    for (; e < gend; ++e) {
        int s = csr_src[e];
        float4 v = ((const float4*)(loc + (size_t)s * DIM))[l];
        a0.x += v.x; a0.y += v.y; a0.z += v.z; a0.w += v.w;
    }
    float4 acc = make_float4((a0.x + a1.x) + (a2.x + a3.x),
                             (a0.y + a1.y) + (a2.y + a3.y),
                             (a0.z + a1.z) + (a2.z + a3.z),
                             (a0.w + a1.w) + (a2.w + a3.w));
    sacc[t] = acc;
    __syncthreads();
    if (t < 128) {
        float4 a = sacc[t], b = sacc[t + 128];
        sacc[t] = make_float4(a.x + b.x, a.y + b.y, a.z + b.z, a.w + b.w);
    }
    __syncthreads();
    if (t < 64) {
        float4 a = sacc[t], b = sacc[t + 64];
        sacc[t] = make_float4(a.x + b.x, a.y + b.y, a.z + b.z, a.w + b.w);
    }
    __syncthreads();
    if (t < 32) {
        float4 a = sacc[t], b = sacc[t + 32];
        srow[4 * t + 0] = a.x + b.x;
        srow[4 * t + 1] = a.y + b.y;
        srow[4 * t + 2] = a.z + b.z;
        srow[4 * t + 3] = a.w + b.w;
    }
    __syncthreads();
    int j = t & 127;
    int h = t >> 7;
    float m0 = 0.f, m1 = 0.f, m2 = 0.f, m3 = 0.f;
    int k0 = h * 64;
    #pragma unroll 4
    for (int k = 0; k < 64; k += 4) {
        m0 += WT[(k0 + k + 0) * DIM + j] * srow[k0 + k + 0];
        m1 += WT[(k0 + k + 1) * DIM + j] * srow[k0 + k + 1];
        m2 += WT[(k0 + k + 2) * DIM + j] * srow[k0 + k + 2];
        m3 += WT[(k0 + k + 3) * DIM + j] * srow[k0 + k + 3];
    }
    float* sred = (float*)sacc;
    sred[t] = (m0 + m1) + (m2 + m3);
    __syncthreads();
    if (t < 128) {
        float v = sred[t] + sred[t + 128] + bias[t];
        v = v > 0.f ? v : NEG_SLOPE * v;
        out[(size_t)c * DIM + t] = v;
    }
}

__launch_bounds__(128)
__global__ void scatter_atomic_kernel(const float* __restrict__ loc, const int* __restrict__ src,
                                      const int* __restrict__ dst, float* __restrict__ agg) {
    int e = blockIdx.x;
    int d = threadIdx.x;
    atomicAdd(&agg[(size_t)dst[e] * DIM + d], loc[(size_t)src[e] * DIM + d]);
}

#define CATS_PER_BLOCK 8
__launch_bounds__(256)
__global__ void gemm_lrelu_kernel(const float* __restrict__ agg, const float* __restrict__ W,
                                  const float* __restrict__ b, float* __restrict__ out) {
    __shared__ float sW[DIM * 129];
    __shared__ float sA[CATS_PER_BLOCK * DIM];
    int t = threadIdx.x;
    int cbase = blockIdx.x * CATS_PER_BLOCK;
    for (int i = t; i < DIM * DIM; i += 256) {
        int j = i >> 7, k = i & 127;
        sW[j * 129 + k] = W[i];
    }
    for (int i = t; i < CATS_PER_BLOCK * DIM; i += 256)
        sA[i] = agg[(size_t)cbase * DIM + i];
    __syncthreads();
    int j = t & 127;
    int cc = t >> 7;
    float acc0 = 0.f, acc1 = 0.f, acc2 = 0.f, acc3 = 0.f;
    for (int k = 0; k < DIM; ++k) {
        float w = sW[j * 129 + k];
        acc0 += w * sA[(cc + 0) * DIM + k];
        acc1 += w * sA[(cc + 2) * DIM + k];
        acc2 += w * sA[(cc + 4) * DIM + k];
        acc3 += w * sA[(cc + 6) * DIM + k];
    }
    float bj = b[j];
    float r0 = acc0 + bj, r1 = acc1 + bj, r2 = acc2 + bj, r3 = acc3 + bj;
    r0 = r0 > 0.f ? r0 : NEG_SLOPE * r0;
    r1 = r1 > 0.f ? r1 : NEG_SLOPE * r1;
    r2 = r2 > 0.f ? r2 : NEG_SLOPE * r2;
    r3 = r3 > 0.f ? r3 : NEG_SLOPE * r3;
    out[(size_t)(cbase + cc + 0) * DIM + j] = r0;
    out[(size_t)(cbase + cc + 2) * DIM + j] = r1;
    out[(size_t)(cbase + cc + 4) * DIM + j] = r2;
    out[(size_t)(cbase + cc + 6) * DIM + j] = r3;
}

extern "C" void kernel_launch(void* const* d_in, const int* in_sizes, int n_in,
                              void* d_out, int out_size, void* d_ws, size_t ws_size,
                              hipStream_t stream) {
    const float* loc  = (const float*)d_in[0];
    const float* W    = (const float*)d_in[1];
    const float* bias = (const float*)d_in[2];
    const int*   esrc = (const int*)d_in[3];
    const int*   edst = (const int*)d_in[4];
    float* out = (float*)d_out;

    size_t need_new  = ((size_t)N_EDGES + (size_t)NB * NC1 + DIM * DIM) * sizeof(int);
    size_t need_rank = ((size_t)2 * N_EDGES + 2 * PAD + DIM * DIM) * sizeof(int);

    if (ws_size >= need_new) {
        int*   csr2  = (int*)d_ws;                         // [N_EDGES] chunk-major, cat-sorted within chunk
        int*   loffg = csr2 + N_EDGES;                     // [NB * (N_CAT+1)] per-chunk offsets
        float* WT    = (float*)(loffg + (size_t)NB * NC1); // [DIM*DIM]

        build_kernel<<<NB + 1, 1024, 0, stream>>>(esrc, edst, W, WT, csr2, loffg);
        agg3_kernel<<<N_CAT, 256, 0, stream>>>(loc, csr2, loffg, WT, bias, out);
    } else if (ws_size >= need_rank) {
        int* counts  = (int*)d_ws;
        int* offsets = counts + PAD;
        float* WT    = (float*)(offsets + PAD);
        int* rank    = (int*)(WT + DIM * DIM);
        int* csr_src = rank + N_EDGES;

        hipMemsetAsync(counts, 0, (size_t)PAD * sizeof(int), stream);
        transpose_kernel<<<DIM, DIM, 0, stream>>>(W, WT);
        const int eblocks = (N_EDGES + 255) / 256;
        hist_rank_kernel<<<eblocks, 256, 0, stream>>>(edst, counts, rank, N_EDGES);
        scan_kernel<<<1, 1024, 0, stream>>>(counts, offsets);
        fill_rank_kernel<<<eblocks, 256, 0, stream>>>(esrc, edst, rank, offsets, csr_src, N_EDGES);
        agg_fused_kernel<<<N_CAT, 256, 0, stream>>>(loc, csr_src, offsets, WT, bias, out);
    } else {
        int n = N_CAT * DIM;
        zero_kernel<<<(n + 255) / 256, 256, 0, stream>>>(out, n);
        scatter_atomic_kernel<<<N_EDGES, DIM, 0, stream>>>(loc, esrc, edst, out);
        gemm_lrelu_kernel<<<N_CAT / CATS_PER_BLOCK, 256, 0, stream>>>(out, W, bias, out);
    }
}